// Round 8
// baseline (110.800 us; speedup 1.0000x reference)
//
#include <hip/hip_runtime.h>
#include <hip/hip_bf16.h>
#include <math.h>

// FraudDetectionNet R8: R5 structure (last-known-good, 109.4us, 4-ulp absmax)
// + U-side-only split-bf16 compensation.
//   U = U_hi(bf16) + U_lo(bf16 residual);  re = psi.U_hi + psi.U_lo via two
//   chained MFMAs, each zero-padded at k>=16 EXACTLY like R5's verified B
//   pattern (A rows stay [psi_hi | zeros], LDS layout unchanged).
//   Removes U's 2^-9 quantization -> expected absmax ~2-3 ulp (was 4).
// Block = 256 threads (4 waves), 16 images. Wave w owns images img0+4w..+3.
// Per wave: 12 full 64-patch chunks + 1 tail chunk (4 images x patches
// 192..195 = 16 lanes, all rows fresh). Wave-private 64-row LDS psi region:
// ds_write -> lgkmcnt -> ds_read, NO __syncthreads in the loop.
// zc[m][n] = sum_w Z[n][w]*w_cls[1+4m+w] precomputed per block (stride 17).

#define NPATCH 196
#define NIMG   8192
#define GIMG   16               // images per block
#define NBLK   (NIMG / GIMG)    // 512
#define ROWB   80               // 32 bf16 (64B) + 16B pad, 16B-aligned rows

typedef __bf16 bf16x8 __attribute__((ext_vector_type(8)));
typedef float  f32x4  __attribute__((ext_vector_type(4)));

union Frag { bf16x8 v; uint4 u; unsigned us[4]; };

static __device__ inline unsigned short bfbits(float f) {
    __hip_bfloat16 h = __float2bfloat16(f);   // RNE
    unsigned short s; __builtin_memcpy(&s, &h, 2); return s;
}
static __device__ inline float bf2f(unsigned short s) {
    unsigned u = (unsigned)s << 16; float f; __builtin_memcpy(&f, &u, 4); return f;
}
static __device__ inline unsigned packbf(float lo, float hi) {
    return (unsigned)bfbits(lo) | ((unsigned)bfbits(hi) << 16);
}
// split pair (v0,v1) into packed bf16 hi word and bf16 residual word
static __device__ inline void split2(float v0, float v1, unsigned& hw, unsigned& lw) {
    const unsigned short h0 = bfbits(v0), h1 = bfbits(v1);
    const unsigned short l0 = bfbits(v0 - bf2f(h0));
    const unsigned short l1 = bfbits(v1 - bf2f(h1));
    hw = (unsigned)h0 | ((unsigned)h1 << 16);
    lw = (unsigned)l0 | ((unsigned)l1 << 16);
}

// psi pack from 4 pixels -> two uint4 (16 bf16)
static __device__ inline void psi_pack(float x0, float x1, float x2, float x3,
                                       uint4& lo, uint4& hi) {
    float s0, c0, s1, c1, s2, c2, s3, c3;
    __sincosf(0.5f * x0, &s0, &c0);
    __sincosf(0.5f * x1, &s1, &c1);
    __sincosf(0.5f * x2, &s2, &c2);
    __sincosf(0.5f * x3, &s3, &c3);
    const float a01[4] = { c0 * c1, c0 * s1, s0 * c1, s0 * s1 };
    const float a23[4] = { c2 * c3, c2 * s3, s2 * c3, s2 * s3 };
    lo.x = packbf(a01[0] * a23[0], a01[0] * a23[1]);
    lo.y = packbf(a01[0] * a23[2], a01[0] * a23[3]);
    lo.z = packbf(a01[1] * a23[0], a01[1] * a23[1]);
    lo.w = packbf(a01[1] * a23[2], a01[1] * a23[3]);
    hi.x = packbf(a01[2] * a23[0], a01[2] * a23[1]);
    hi.y = packbf(a01[2] * a23[2], a01[2] * a23[3]);
    hi.z = packbf(a01[3] * a23[0], a01[3] * a23[1]);
    hi.w = packbf(a01[3] * a23[2], a01[3] * a23[3]);
}

__global__ __launch_bounds__(256) void fraud_kernel(
    const float* __restrict__ x,        // (8192, 784)
    const float* __restrict__ w_in,     // (2,2)
    const float* __restrict__ b_in,     // (2,)
    const float* __restrict__ scale_in, // (2,)
    const float* __restrict__ shift_in, // (2,)
    const float* __restrict__ Wc,       // (2,2,2)
    const float* __restrict__ bc,       // (2,2)
    const float* __restrict__ scalec,   // (2,2)
    const float* __restrict__ shiftc,   // (2,2)
    const float* __restrict__ w_out,    // (1,2)
    const float* __restrict__ b_out,    // (1,)
    const float* __restrict__ U_re,     // (16,16)
    const float* __restrict__ U_im,     // (16,16)
    const float* __restrict__ w_cls,    // (785,)
    const float* __restrict__ b_cls,    // (1,)
    float* __restrict__ out)            // (8192,)
{
    __shared__ __align__(16) unsigned char lds[256 * ROWB];  // 20 KB psi rows
    __shared__ float zc[NPATCH * 17];                        // 13.3 KB
    __shared__ float accS[GIMG], accV[GIMG], accQ[GIMG];

    const int tid  = threadIdx.x;
    const int lane = tid & 63;
    const int wv   = tid >> 6;
    const int n16  = lane & 15;
    const int q    = lane >> 4;
    const int img0 = blockIdx.x * GIMG;

    // ---- zc table: zc[m*17+n] = sum_w (1-2*bit_{3-w}(n)) * w_cls[1+4m+w] ----
    for (int i = tid; i < NPATCH * 16; i += 256) {
        const int m = i >> 4, n = i & 15;
        const float* wp = w_cls + 1 + 4 * m;
        const float w0 = wp[0], w1 = wp[1], w2 = wp[2], w3 = wp[3];
        zc[m * 17 + n] = ((n & 8) ? -w0 : w0) + ((n & 4) ? -w1 : w1)
                       + ((n & 2) ? -w2 : w2) + ((n & 1) ? -w3 : w3);
    }

    // ---- B fragments: B[k][n] = U[n][k] split hi+lo, k = q*8+j (k>=16 zero) ----
    Frag breh, brel, bimh, biml;
    breh.u = make_uint4(0u, 0u, 0u, 0u);
    brel.u = make_uint4(0u, 0u, 0u, 0u);
    bimh.u = make_uint4(0u, 0u, 0u, 0u);
    biml.u = make_uint4(0u, 0u, 0u, 0u);
    if (q < 2) {
        const float* pr = U_re + n16 * 16 + q * 8;
        const float* pi = U_im + n16 * 16 + q * 8;
        #pragma unroll
        for (int jj = 0; jj < 4; ++jj) {
            split2(pr[2 * jj], pr[2 * jj + 1], breh.us[jj], brel.us[jj]);
            split2(pi[2 * jj], pi[2 * jj + 1], bimh.us[jj], biml.us[jj]);
        }
    }

    // zero-pad k=16..31 of own row ONCE (never overwritten)
    unsigned char* wbase = lds + wv * 64 * ROWB;
    unsigned* myrow = (unsigned*)(wbase + lane * ROWB);
    *(uint4*)(myrow + 8)  = make_uint4(0u, 0u, 0u, 0u);
    *(uint4*)(myrow + 12) = make_uint4(0u, 0u, 0u, 0u);

    __syncthreads();   // zc table ready

    const int imgw0 = img0 + wv * 4;   // this wave's first image

    // ---- prefetch chunk idx=0 pixels (image imgw0, patch = lane) ----
    float2 ctop, cbot;
    {
        const int p = lane, rr = p / 14, cc = p - rr * 14;
        const float* xp = x + (size_t)imgw0 * 784;
        ctop = *(const float2*)(xp + (2 * rr) * 28 + 2 * cc);
        cbot = *(const float2*)(xp + (2 * rr + 1) * 28 + 2 * cc);
    }

    float rS = 0.f, rV = 0.f, rQ = 0.f;

    #pragma unroll 3
    for (int idx = 0; idx < 12; ++idx) {
        const int im = idx / 3;            // wave-local image 0..3
        const int c  = idx - im * 3;       // chunk 0..2
        const float x0 = ctop.x, x1 = ctop.y, x2 = cbot.x, x3 = cbot.y;

        // prefetch next chunk
        if (idx < 11) {
            const int nidx = idx + 1;
            const int nim = nidx / 3, nc = nidx - nim * 3;
            const int p = nc * 64 + lane, rr = p / 14, cc = p - rr * 14;
            const float* xp = x + (size_t)(imgw0 + nim) * 784;
            ctop = *(const float2*)(xp + (2 * rr) * 28 + 2 * cc);
            cbot = *(const float2*)(xp + (2 * rr + 1) * 28 + 2 * cc);
        }

        rS += x0 + x1 + x2 + x3;
        rV += x0 * x0 + x1 * x1 + x2 * x2 + x3 * x3;

        uint4 lo, hi;
        psi_pack(x0, x1, x2, x3, lo, hi);
        *(uint4*)(myrow)     = lo;
        *(uint4*)(myrow + 4) = hi;
        asm volatile("s_waitcnt lgkmcnt(0)" ::: "memory");

        #pragma unroll
        for (int t = 0; t < 4; ++t) {
            Frag a;   // A[m=n16][k=q*8+j] of this 16-row tile
            a.u = *(const uint4*)(wbase + (t * 16 + n16) * ROWB + q * 16);
            f32x4 cr = {0.f, 0.f, 0.f, 0.f}, ci = {0.f, 0.f, 0.f, 0.f};
            cr = __builtin_amdgcn_mfma_f32_16x16x32_bf16(a.v, breh.v, cr, 0, 0, 0);
            cr = __builtin_amdgcn_mfma_f32_16x16x32_bf16(a.v, brel.v, cr, 0, 0, 0);
            ci = __builtin_amdgcn_mfma_f32_16x16x32_bf16(a.v, bimh.v, ci, 0, 0, 0);
            ci = __builtin_amdgcn_mfma_f32_16x16x32_bf16(a.v, biml.v, ci, 0, 0, 0);
            const int pb = (c * 64 + t * 16 + q * 4) * 17 + n16;
            #pragma unroll
            for (int j = 0; j < 4; ++j) {
                const float prob = cr[j] * cr[j] + ci[j] * ci[j];
                rQ = fmaf(prob, zc[pb + 17 * j], rQ);
            }
        }

        if (c == 2) {   // image finished: reduce & store
            #pragma unroll
            for (int off = 1; off < 64; off <<= 1) {
                rS += __shfl_xor(rS, off, 64);
                rV += __shfl_xor(rV, off, 64);
                rQ += __shfl_xor(rQ, off, 64);
            }
            if (lane == 0) {
                accS[wv * 4 + im] = rS;
                accV[wv * 4 + im] = rV;
                accQ[wv * 4 + im] = rQ;
            }
            rS = 0.f; rV = 0.f; rQ = 0.f;
        }
    }

    // ---- tail chunk: 4 images x patches 192..195, lanes 0..15 ----
    float tS = 0.f, tV = 0.f;
    if (lane < 16) {
        const int iml = lane >> 2;            // wave-local image
        const int p   = 192 + (lane & 3);
        const int rr = p / 14, cc = p - rr * 14;
        const float* xp = x + (size_t)(imgw0 + iml) * 784;
        const float2 top = *(const float2*)(xp + (2 * rr) * 28 + 2 * cc);
        const float2 bot = *(const float2*)(xp + (2 * rr + 1) * 28 + 2 * cc);
        const float x0 = top.x, x1 = top.y, x2 = bot.x, x3 = bot.y;
        tS = x0 + x1 + x2 + x3;
        tV = x0 * x0 + x1 * x1 + x2 * x2 + x3 * x3;
        uint4 lo, hi;
        psi_pack(x0, x1, x2, x3, lo, hi);
        *(uint4*)(myrow)     = lo;    // row l holds (img l>>2, patch 192+(l&3))
        *(uint4*)(myrow + 4) = hi;
    }
    asm volatile("s_waitcnt lgkmcnt(0)" ::: "memory");

    float tQ = 0.f;
    {
        Frag a;   // tile 0 only: rows 0..15 all fresh
        a.u = *(const uint4*)(wbase + n16 * ROWB + q * 16);
        f32x4 cr = {0.f, 0.f, 0.f, 0.f}, ci = {0.f, 0.f, 0.f, 0.f};
        cr = __builtin_amdgcn_mfma_f32_16x16x32_bf16(a.v, breh.v, cr, 0, 0, 0);
        cr = __builtin_amdgcn_mfma_f32_16x16x32_bf16(a.v, brel.v, cr, 0, 0, 0);
        ci = __builtin_amdgcn_mfma_f32_16x16x32_bf16(a.v, bimh.v, ci, 0, 0, 0);
        ci = __builtin_amdgcn_mfma_f32_16x16x32_bf16(a.v, biml.v, ci, 0, 0, 0);
        // lane (q,n16) holds prob[m=q*4+j][n16]: image q, patch 192+j
        #pragma unroll
        for (int j = 0; j < 4; ++j) {
            const float prob = cr[j] * cr[j] + ci[j] * ci[j];
            tQ = fmaf(prob, zc[(192 + j) * 17 + n16], tQ);
        }
    }
    // pixel sums: reduce within 4-lane groups (image = lane>>2 for lanes<16)
    tS += __shfl_xor(tS, 1, 64);  tS += __shfl_xor(tS, 2, 64);
    tV += __shfl_xor(tV, 1, 64);  tV += __shfl_xor(tV, 2, 64);
    // quantum: reduce within 16-lane groups (image = q)
    tQ += __shfl_xor(tQ, 1, 64);  tQ += __shfl_xor(tQ, 2, 64);
    tQ += __shfl_xor(tQ, 4, 64);  tQ += __shfl_xor(tQ, 8, 64);

    if (lane < 16 && (lane & 3) == 0) {       // one lane per image
        const int iml = lane >> 2;
        accS[wv * 4 + iml] += tS;
        accV[wv * 4 + iml] += tV;
    }
    if (n16 == 0) {                            // lanes 0,16,32,48 -> image q
        accQ[wv * 4 + q] += tQ;
    }
    __syncthreads();

    // ---- final: 16 threads, one image each ----
    if (tid < GIMG) {
        const float S  = accS[tid];
        const float SS = accV[tid];
        const float QS = accQ[tid];

        const float mean = S * (1.f / 784.f);
        float var = (SS - S * S * (1.f / 784.f)) * (1.f / 783.f);  // ddof=1
        var = fmaxf(var, 0.f);
        const float stdv = sqrtf(var);

        float h0 = mean, h1 = stdv;
        {
            const float t0 = tanhf(h0 * w_in[0] + h1 * w_in[1] + b_in[0]);
            const float t1 = tanhf(h0 * w_in[2] + h1 * w_in[3] + b_in[1]);
            h0 = t0 * scale_in[0] + shift_in[0];
            h1 = t1 * scale_in[1] + shift_in[1];
        }
        #pragma unroll
        for (int l = 0; l < 2; ++l) {
            const float t0 = tanhf(h0 * Wc[l * 4 + 0] + h1 * Wc[l * 4 + 1] + bc[l * 2 + 0]);
            const float t1 = tanhf(h0 * Wc[l * 4 + 2] + h1 * Wc[l * 4 + 3] + bc[l * 2 + 1]);
            h0 = t0 * scalec[l * 2 + 0] + shiftc[l * 2 + 0];
            h1 = t1 * scalec[l * 2 + 1] + shiftc[l * 2 + 1];
        }
        const float cls   = h0 * w_out[0] + h1 * w_out[1] + b_out[0];
        const float logit = b_cls[0] + w_cls[0] * cls + QS;
        out[img0 + tid] = 1.f / (1.f + __expf(-logit));
    }
}

extern "C" void kernel_launch(void* const* d_in, const int* in_sizes, int n_in,
                              void* d_out, int out_size, void* d_ws, size_t ws_size,
                              hipStream_t stream) {
    const float* x        = (const float*)d_in[0];
    const float* w_in     = (const float*)d_in[1];
    const float* b_in     = (const float*)d_in[2];
    const float* scale_in = (const float*)d_in[3];
    const float* shift_in = (const float*)d_in[4];
    const float* Wc       = (const float*)d_in[5];
    const float* bc       = (const float*)d_in[6];
    const float* scalec   = (const float*)d_in[7];
    const float* shiftc   = (const float*)d_in[8];
    const float* w_out    = (const float*)d_in[9];
    const float* b_out    = (const float*)d_in[10];
    const float* U_re     = (const float*)d_in[11];
    const float* U_im     = (const float*)d_in[12];
    const float* w_cls    = (const float*)d_in[13];
    const float* b_cls    = (const float*)d_in[14];
    float* out = (float*)d_out;

    fraud_kernel<<<NBLK, 256, 0, stream>>>(x, w_in, b_in, scale_in, shift_in,
                                           Wc, bc, scalec, shiftc, w_out, b_out,
                                           U_re, U_im, w_cls, b_cls, out);
}

// Round 9
// 108.938 us; speedup vs baseline: 1.0171x; 1.0171x over previous
//
#include <hip/hip_runtime.h>
#include <hip/hip_bf16.h>
#include <math.h>

// FraudDetectionNet R9 == R5 (empirical optimum: 109.4us, absmax 0.0078).
// Single dispatch, 16 images/block, barrier-free main loop.
// Block = 256 threads (4 waves), 16 images. Wave w owns images img0+4w..+3.
// Per wave: 12 full chunks (image im, patches c*64..c*64+63; all 64 lanes
// active, single image -> register accumulation, one reduce per image) +
// 1 tail chunk (4 images x patches 192..195 = 16 lanes).
// Each wave uses its private 64-row LDS psi region: ds_write -> lgkmcnt ->
// ds_read within the wave, NO __syncthreads in the loop.
// zc[m][n] = sum_w Z[n][w]*w_cls[1+4m+w] precomputed once per block
// (stride-17 LDS table). Epilogue: prob (MFMA C-layout) * zc -> register acc.
// Final: threads 0..15 run mean/std -> tanh MLP -> +QS -> sigmoid.
// NOTE (accuracy): bf16 psi/U give absmax 4 output-ulp vs 6.76-ulp threshold.
// Split-bf16 compensation variants (R7/R8) did NOT reduce the max error —
// it is dominated by psi quantization + codegen contraction noise — and two
// restructures (R6/R7) failed at 7-8 ulp. Do not restructure this loop
// without re-checking absmax.

#define NPATCH 196
#define NIMG   8192
#define GIMG   16               // images per block
#define NBLK   (NIMG / GIMG)    // 512
#define ROWB   80               // 32 bf16 (64B) + 16B pad, 16B-aligned rows

typedef __bf16 bf16x8 __attribute__((ext_vector_type(8)));
typedef float  f32x4  __attribute__((ext_vector_type(4)));

union Frag { bf16x8 v; uint4 u; unsigned us[4]; };

static __device__ inline unsigned short bfbits(float f) {
    __hip_bfloat16 h = __float2bfloat16(f);   // RNE
    unsigned short s; __builtin_memcpy(&s, &h, 2); return s;
}
static __device__ inline unsigned packbf(float lo, float hi) {
    return (unsigned)bfbits(lo) | ((unsigned)bfbits(hi) << 16);
}

// psi pack from 4 pixels -> two uint4 (16 bf16)
static __device__ inline void psi_pack(float x0, float x1, float x2, float x3,
                                       uint4& lo, uint4& hi) {
    float s0, c0, s1, c1, s2, c2, s3, c3;
    __sincosf(0.5f * x0, &s0, &c0);
    __sincosf(0.5f * x1, &s1, &c1);
    __sincosf(0.5f * x2, &s2, &c2);
    __sincosf(0.5f * x3, &s3, &c3);
    const float a01[4] = { c0 * c1, c0 * s1, s0 * c1, s0 * s1 };
    const float a23[4] = { c2 * c3, c2 * s3, s2 * c3, s2 * s3 };
    lo.x = packbf(a01[0] * a23[0], a01[0] * a23[1]);
    lo.y = packbf(a01[0] * a23[2], a01[0] * a23[3]);
    lo.z = packbf(a01[1] * a23[0], a01[1] * a23[1]);
    lo.w = packbf(a01[1] * a23[2], a01[1] * a23[3]);
    hi.x = packbf(a01[2] * a23[0], a01[2] * a23[1]);
    hi.y = packbf(a01[2] * a23[2], a01[2] * a23[3]);
    hi.z = packbf(a01[3] * a23[0], a01[3] * a23[1]);
    hi.w = packbf(a01[3] * a23[2], a01[3] * a23[3]);
}

__global__ __launch_bounds__(256) void fraud_kernel(
    const float* __restrict__ x,        // (8192, 784)
    const float* __restrict__ w_in,     // (2,2)
    const float* __restrict__ b_in,     // (2,)
    const float* __restrict__ scale_in, // (2,)
    const float* __restrict__ shift_in, // (2,)
    const float* __restrict__ Wc,       // (2,2,2)
    const float* __restrict__ bc,       // (2,2)
    const float* __restrict__ scalec,   // (2,2)
    const float* __restrict__ shiftc,   // (2,2)
    const float* __restrict__ w_out,    // (1,2)
    const float* __restrict__ b_out,    // (1,)
    const float* __restrict__ U_re,     // (16,16)
    const float* __restrict__ U_im,     // (16,16)
    const float* __restrict__ w_cls,    // (785,)
    const float* __restrict__ b_cls,    // (1,)
    float* __restrict__ out)            // (8192,)
{
    __shared__ __align__(16) unsigned char lds[256 * ROWB];  // 20 KB psi rows
    __shared__ float zc[NPATCH * 17];                        // 13.3 KB
    __shared__ float accS[GIMG], accV[GIMG], accQ[GIMG];

    const int tid  = threadIdx.x;
    const int lane = tid & 63;
    const int wv   = tid >> 6;
    const int n16  = lane & 15;
    const int q    = lane >> 4;
    const int img0 = blockIdx.x * GIMG;

    // ---- zc table: zc[m*17+n] = sum_w (1-2*bit_{3-w}(n)) * w_cls[1+4m+w] ----
    for (int i = tid; i < NPATCH * 16; i += 256) {
        const int m = i >> 4, n = i & 15;
        const float* wp = w_cls + 1 + 4 * m;
        const float w0 = wp[0], w1 = wp[1], w2 = wp[2], w3 = wp[3];
        zc[m * 17 + n] = ((n & 8) ? -w0 : w0) + ((n & 4) ? -w1 : w1)
                       + ((n & 2) ? -w2 : w2) + ((n & 1) ? -w3 : w3);
    }

    // ---- B fragments: B[k][n] = U[n][k], k = q*8+j (k>=16 zero) ----
    Frag bre, bim;
    bre.u = make_uint4(0u, 0u, 0u, 0u);
    bim.u = make_uint4(0u, 0u, 0u, 0u);
    if (q < 2) {
        const float* pr = U_re + n16 * 16 + q * 8;
        const float* pi = U_im + n16 * 16 + q * 8;
        bre.us[0] = packbf(pr[0], pr[1]); bre.us[1] = packbf(pr[2], pr[3]);
        bre.us[2] = packbf(pr[4], pr[5]); bre.us[3] = packbf(pr[6], pr[7]);
        bim.us[0] = packbf(pi[0], pi[1]); bim.us[1] = packbf(pi[2], pi[3]);
        bim.us[2] = packbf(pi[4], pi[5]); bim.us[3] = packbf(pi[6], pi[7]);
    }

    // zero-pad k=16..31 of own row ONCE (never overwritten)
    unsigned char* wbase = lds + wv * 64 * ROWB;
    unsigned* myrow = (unsigned*)(wbase + lane * ROWB);
    *(uint4*)(myrow + 8)  = make_uint4(0u, 0u, 0u, 0u);
    *(uint4*)(myrow + 12) = make_uint4(0u, 0u, 0u, 0u);

    __syncthreads();   // zc table ready

    const int imgw0 = img0 + wv * 4;   // this wave's first image

    // ---- prefetch chunk idx=0 pixels (image imgw0, patch = lane) ----
    float2 ctop, cbot;
    {
        const int p = lane, rr = p / 14, cc = p - rr * 14;
        const float* xp = x + (size_t)imgw0 * 784;
        ctop = *(const float2*)(xp + (2 * rr) * 28 + 2 * cc);
        cbot = *(const float2*)(xp + (2 * rr + 1) * 28 + 2 * cc);
    }

    float rS = 0.f, rV = 0.f, rQ = 0.f;

    #pragma unroll 3
    for (int idx = 0; idx < 12; ++idx) {
        const int im = idx / 3;            // wave-local image 0..3
        const int c  = idx - im * 3;       // chunk 0..2
        const float x0 = ctop.x, x1 = ctop.y, x2 = cbot.x, x3 = cbot.y;

        // prefetch next chunk
        if (idx < 11) {
            const int nidx = idx + 1;
            const int nim = nidx / 3, nc = nidx - nim * 3;
            const int p = nc * 64 + lane, rr = p / 14, cc = p - rr * 14;
            const float* xp = x + (size_t)(imgw0 + nim) * 784;
            ctop = *(const float2*)(xp + (2 * rr) * 28 + 2 * cc);
            cbot = *(const float2*)(xp + (2 * rr + 1) * 28 + 2 * cc);
        }

        rS += x0 + x1 + x2 + x3;
        rV += x0 * x0 + x1 * x1 + x2 * x2 + x3 * x3;

        uint4 lo, hi;
        psi_pack(x0, x1, x2, x3, lo, hi);
        *(uint4*)(myrow)     = lo;
        *(uint4*)(myrow + 4) = hi;
        asm volatile("s_waitcnt lgkmcnt(0)" ::: "memory");

        #pragma unroll
        for (int t = 0; t < 4; ++t) {
            Frag a;   // A[m=n16][k=q*8+j] of this 16-row tile
            a.u = *(const uint4*)(wbase + (t * 16 + n16) * ROWB + q * 16);
            f32x4 cr = {0.f, 0.f, 0.f, 0.f}, ci = {0.f, 0.f, 0.f, 0.f};
            cr = __builtin_amdgcn_mfma_f32_16x16x32_bf16(a.v, bre.v, cr, 0, 0, 0);
            ci = __builtin_amdgcn_mfma_f32_16x16x32_bf16(a.v, bim.v, ci, 0, 0, 0);
            const int pb = (c * 64 + t * 16 + q * 4) * 17 + n16;
            #pragma unroll
            for (int j = 0; j < 4; ++j) {
                const float prob = cr[j] * cr[j] + ci[j] * ci[j];
                rQ = fmaf(prob, zc[pb + 17 * j], rQ);
            }
        }

        if (c == 2) {   // image finished: reduce & store
            #pragma unroll
            for (int off = 1; off < 64; off <<= 1) {
                rS += __shfl_xor(rS, off, 64);
                rV += __shfl_xor(rV, off, 64);
                rQ += __shfl_xor(rQ, off, 64);
            }
            if (lane == 0) {
                accS[wv * 4 + im] = rS;
                accV[wv * 4 + im] = rV;
                accQ[wv * 4 + im] = rQ;
            }
            rS = 0.f; rV = 0.f; rQ = 0.f;
        }
    }

    // ---- tail chunk: 4 images x patches 192..195, lanes 0..15 ----
    float tS = 0.f, tV = 0.f;
    if (lane < 16) {
        const int iml = lane >> 2;            // wave-local image
        const int p   = 192 + (lane & 3);
        const int rr = p / 14, cc = p - rr * 14;
        const float* xp = x + (size_t)(imgw0 + iml) * 784;
        const float2 top = *(const float2*)(xp + (2 * rr) * 28 + 2 * cc);
        const float2 bot = *(const float2*)(xp + (2 * rr + 1) * 28 + 2 * cc);
        const float x0 = top.x, x1 = top.y, x2 = bot.x, x3 = bot.y;
        tS = x0 + x1 + x2 + x3;
        tV = x0 * x0 + x1 * x1 + x2 * x2 + x3 * x3;
        uint4 lo, hi;
        psi_pack(x0, x1, x2, x3, lo, hi);
        *(uint4*)(myrow)     = lo;    // row l holds (img l>>2, patch 192+(l&3))
        *(uint4*)(myrow + 4) = hi;
    }
    asm volatile("s_waitcnt lgkmcnt(0)" ::: "memory");

    float tQ = 0.f;
    {
        Frag a;   // tile 0 only: rows 0..15
        a.u = *(const uint4*)(wbase + n16 * ROWB + q * 16);
        f32x4 cr = {0.f, 0.f, 0.f, 0.f}, ci = {0.f, 0.f, 0.f, 0.f};
        cr = __builtin_amdgcn_mfma_f32_16x16x32_bf16(a.v, bre.v, cr, 0, 0, 0);
        ci = __builtin_amdgcn_mfma_f32_16x16x32_bf16(a.v, bim.v, ci, 0, 0, 0);
        // lane (q,n16) holds prob[m=q*4+j][n16]: image q, patch 192+j
        #pragma unroll
        for (int j = 0; j < 4; ++j) {
            const float prob = cr[j] * cr[j] + ci[j] * ci[j];
            tQ = fmaf(prob, zc[(192 + j) * 17 + n16], tQ);
        }
    }
    // pixel sums: reduce within 4-lane groups (image = lane>>2 for lanes<16)
    tS += __shfl_xor(tS, 1, 64);  tS += __shfl_xor(tS, 2, 64);
    tV += __shfl_xor(tV, 1, 64);  tV += __shfl_xor(tV, 2, 64);
    // quantum: reduce within 16-lane groups (image = q)
    tQ += __shfl_xor(tQ, 1, 64);  tQ += __shfl_xor(tQ, 2, 64);
    tQ += __shfl_xor(tQ, 4, 64);  tQ += __shfl_xor(tQ, 8, 64);

    if (lane < 16 && (lane & 3) == 0) {       // one lane per image
        const int iml = lane >> 2;
        accS[wv * 4 + iml] += tS;
        accV[wv * 4 + iml] += tV;
    }
    if (n16 == 0) {                            // lanes 0,16,32,48 -> image q
        accQ[wv * 4 + q] += tQ;
    }
    __syncthreads();

    // ---- final: 16 threads, one image each ----
    if (tid < GIMG) {
        const float S  = accS[tid];
        const float SS = accV[tid];
        const float QS = accQ[tid];

        const float mean = S * (1.f / 784.f);
        float var = (SS - S * S * (1.f / 784.f)) * (1.f / 783.f);  // ddof=1
        var = fmaxf(var, 0.f);
        const float stdv = sqrtf(var);

        float h0 = mean, h1 = stdv;
        {
            const float t0 = tanhf(h0 * w_in[0] + h1 * w_in[1] + b_in[0]);
            const float t1 = tanhf(h0 * w_in[2] + h1 * w_in[3] + b_in[1]);
            h0 = t0 * scale_in[0] + shift_in[0];
            h1 = t1 * scale_in[1] + shift_in[1];
        }
        #pragma unroll
        for (int l = 0; l < 2; ++l) {
            const float t0 = tanhf(h0 * Wc[l * 4 + 0] + h1 * Wc[l * 4 + 1] + bc[l * 2 + 0]);
            const float t1 = tanhf(h0 * Wc[l * 4 + 2] + h1 * Wc[l * 4 + 3] + bc[l * 2 + 1]);
            h0 = t0 * scalec[l * 2 + 0] + shiftc[l * 2 + 0];
            h1 = t1 * scalec[l * 2 + 1] + shiftc[l * 2 + 1];
        }
        const float cls   = h0 * w_out[0] + h1 * w_out[1] + b_out[0];
        const float logit = b_cls[0] + w_cls[0] * cls + QS;
        out[img0 + tid] = 1.f / (1.f + __expf(-logit));
    }
}

extern "C" void kernel_launch(void* const* d_in, const int* in_sizes, int n_in,
                              void* d_out, int out_size, void* d_ws, size_t ws_size,
                              hipStream_t stream) {
    const float* x        = (const float*)d_in[0];
    const float* w_in     = (const float*)d_in[1];
    const float* b_in     = (const float*)d_in[2];
    const float* scale_in = (const float*)d_in[3];
    const float* shift_in = (const float*)d_in[4];
    const float* Wc       = (const float*)d_in[5];
    const float* bc       = (const float*)d_in[6];
    const float* scalec   = (const float*)d_in[7];
    const float* shiftc   = (const float*)d_in[8];
    const float* w_out    = (const float*)d_in[9];
    const float* b_out    = (const float*)d_in[10];
    const float* U_re     = (const float*)d_in[11];
    const float* U_im     = (const float*)d_in[12];
    const float* w_cls    = (const float*)d_in[13];
    const float* b_cls    = (const float*)d_in[14];
    float* out = (float*)d_out;

    fraud_kernel<<<NBLK, 256, 0, stream>>>(x, w_in, b_in, scale_in, shift_in,
                                           Wc, bc, scalec, shiftc, w_out, b_out,
                                           U_re, U_im, w_cls, b_cls, out);
}